// Round 1
// baseline (72.404 us; speedup 1.0000x reference)
//
#include <hip/hip_runtime.h>

#define BATCH 8
#define NPTS  4096
#define TPB   256
#define TILES (NPTS / TPB)   // 16 row-tiles per batch

// One block: 256 query points (registers) x 4096 target points (LDS).
// dir 0: query=preds, target=gts  (loss_1: per-pred min over gts)
// dir 1: query=gts,  target=preds (loss_2: per-gt  min over preds)
__global__ __launch_bounds__(TPB) void chamfer_kernel(
    const float* __restrict__ preds,
    const float* __restrict__ gts,
    float* __restrict__ out)
{
    const int dir  = (blockIdx.x >= BATCH * TILES) ? 1 : 0;
    const int bt   = blockIdx.x - dir * BATCH * TILES;
    const int b    = bt / TILES;
    const int tile = bt % TILES;

    const float* A  = dir ? gts   : preds;   // query set
    const float* Bp = dir ? preds : gts;     // target set

    __shared__ float4 sB[NPTS];              // 64 KiB: (y0,y1,y2, y.y)

    const float* Bb = Bp + (size_t)b * NPTS * 3;
    for (int j = threadIdx.x; j < NPTS; j += TPB) {
        const float y0 = Bb[j * 3 + 0];
        const float y1 = Bb[j * 3 + 1];
        const float y2 = Bb[j * 3 + 2];
        sB[j] = make_float4(y0, y1, y2, y0 * y0 + y1 * y1 + y2 * y2);
    }
    __syncthreads();

    const int i = tile * TPB + threadIdx.x;
    const float* Ap = A + ((size_t)b * NPTS + i) * 3;
    const float x0 = Ap[0], x1 = Ap[1], x2 = Ap[2];
    const float rx = x0 * x0 + x1 * x1 + x2 * x2;

    // 4 independent min chains to expose ILP (single wave/SIMD here).
    float best0 = 3.4e38f, best1 = 3.4e38f, best2 = 3.4e38f, best3 = 3.4e38f;
    #pragma unroll 4
    for (int j = 0; j < NPTS; j += 4) {
        {
            const float4 y = sB[j + 0];
            const float t = fmaf(x2, y.z, fmaf(x1, y.y, x0 * y.x));
            best0 = fminf(best0, fmaf(-2.0f, t, rx + y.w));
        }
        {
            const float4 y = sB[j + 1];
            const float t = fmaf(x2, y.z, fmaf(x1, y.y, x0 * y.x));
            best1 = fminf(best1, fmaf(-2.0f, t, rx + y.w));
        }
        {
            const float4 y = sB[j + 2];
            const float t = fmaf(x2, y.z, fmaf(x1, y.y, x0 * y.x));
            best2 = fminf(best2, fmaf(-2.0f, t, rx + y.w));
        }
        {
            const float4 y = sB[j + 3];
            const float t = fmaf(x2, y.z, fmaf(x1, y.y, x0 * y.x));
            best3 = fminf(best3, fmaf(-2.0f, t, rx + y.w));
        }
    }
    float s = fminf(fminf(best0, best1), fminf(best2, best3));

    // Block sum of per-point mins: 64-lane wave reduce, then cross-wave via LDS.
    #pragma unroll
    for (int off = 32; off > 0; off >>= 1)
        s += __shfl_down(s, off, 64);

    __shared__ float red[TPB / 64];
    const int lane = threadIdx.x & 63;
    const int wid  = threadIdx.x >> 6;
    if (lane == 0) red[wid] = s;
    __syncthreads();
    if (threadIdx.x == 0) {
        float t = 0.0f;
        #pragma unroll
        for (int w = 0; w < TPB / 64; ++w) t += red[w];
        atomicAdd(out, t);
    }
}

extern "C" void kernel_launch(void* const* d_in, const int* in_sizes, int n_in,
                              void* d_out, int out_size, void* d_ws, size_t ws_size,
                              hipStream_t stream) {
    const float* preds = (const float*)d_in[0];
    const float* gts   = (const float*)d_in[1];
    float* out = (float*)d_out;

    // d_out is poisoned once before timing and never re-poisoned; we
    // accumulate with atomics, so zero it every call (capturable async op).
    hipMemsetAsync(out, 0, sizeof(float), stream);

    dim3 grid(BATCH * TILES * 2);
    chamfer_kernel<<<grid, TPB, 0, stream>>>(preds, gts, out);
}

// Round 2
// 65.290 us; speedup vs baseline: 1.1090x; 1.1090x over previous
//
#include <hip/hip_runtime.h>

#define BATCH  8
#define NPTS   4096
#define NSLICE 16                 // target-set split per (dir,b)
#define SLICE  (NPTS / NSLICE)    // 256 targets per block
#define TPB1   512                // 8 waves/block, 1 block/CU -> 2 waves/SIMD
#define QPT    8                  // queries per thread (4096 / 512)
#define BIAS   1000.0f            // makes e positive -> uint-ordered atomicMin

// Stage 1: grid = 2 dirs x 8 batches x 16 target-slices = 256 blocks.
// Each thread holds 8 queries in registers; block stages its 256-target
// slice in LDS packed as (-2y0,-2y1,-2y2,||y||^2). Inner loop: 1 broadcast
// ds_read_b128 feeds 8x(3 fma + 1 min) = 32 VALU instrs.
__global__ __launch_bounds__(TPB1, 2) void chamfer_stage1(
    const float* __restrict__ preds,
    const float* __restrict__ gts,
    unsigned int* __restrict__ umin)
{
    const int blk   = blockIdx.x;
    const int slice = blk % NSLICE;
    const int db    = blk / NSLICE;    // dir*8 + b
    const int dir   = db >> 3;
    const int b     = db & 7;

    const float* Q = dir ? gts   : preds;   // query set
    const float* T = dir ? preds : gts;     // target set

    __shared__ float4 sT[SLICE];            // 4 KiB

    const float* Tb = T + ((size_t)b * NPTS + slice * SLICE) * 3;
    for (int j = threadIdx.x; j < SLICE; j += TPB1) {
        const float y0 = Tb[j * 3 + 0];
        const float y1 = Tb[j * 3 + 1];
        const float y2 = Tb[j * 3 + 2];
        sT[j] = make_float4(-2.0f * y0, -2.0f * y1, -2.0f * y2,
                            y0 * y0 + y1 * y1 + y2 * y2);
    }

    // Load this thread's 8 consecutive queries (24 floats, 16B-aligned).
    const int q0 = threadIdx.x * QPT;
    const float* Qb = Q + ((size_t)b * NPTS + q0) * 3;
    float f[24];
    {
        const float4* p4 = reinterpret_cast<const float4*>(Qb);
        float4* f4 = reinterpret_cast<float4*>(f);
        #pragma unroll
        for (int i = 0; i < 6; ++i) f4[i] = p4[i];
    }
    float qx[QPT], qy[QPT], qz[QPT];
    #pragma unroll
    for (int k = 0; k < QPT; ++k) {
        qx[k] = f[k * 3 + 0];
        qy[k] = f[k * 3 + 1];
        qz[k] = f[k * 3 + 2];
    }

    __syncthreads();

    float m[QPT];
    #pragma unroll
    for (int k = 0; k < QPT; ++k) m[k] = 3.4e38f;

    #pragma unroll 4
    for (int j = 0; j < SLICE; ++j) {
        const float4 y = sT[j];
        #pragma unroll
        for (int k = 0; k < QPT; ++k) {
            // e = ||q-y||^2 - ||q||^2 = ry - 2*dot  (rx folded out, added in stage 2)
            const float e = fmaf(qx[k], y.x,
                             fmaf(qy[k], y.y,
                              fmaf(qz[k], y.z, y.w)));
            m[k] = fminf(m[k], e);
        }
    }

    // Combine partial mins across the 16 slices via uint atomicMin
    // (e + BIAS > 0, so the float bit pattern is uint-order-preserving).
    unsigned int* base = umin + (size_t)db * NPTS + q0;
    #pragma unroll
    for (int k = 0; k < QPT; ++k) {
        atomicMin(&base[k], __float_as_uint(m[k] + BIAS));
    }
}

// Stage 2: one thread per query; unbias, add rx, block-reduce, atomicAdd.
#define TPB2 256
__global__ __launch_bounds__(TPB2) void chamfer_stage2(
    const float* __restrict__ preds,
    const float* __restrict__ gts,
    const unsigned int* __restrict__ umin,
    float* __restrict__ out)
{
    const int g   = blockIdx.x * TPB2 + threadIdx.x;   // [0, 2*8*4096)
    const int db  = g >> 12;
    const int dir = db >> 3;
    const float* Q = dir ? gts : preds;
    const int bq  = ((db & 7) << 12) | (g & (NPTS - 1));

    const float x0 = Q[bq * 3 + 0];
    const float x1 = Q[bq * 3 + 1];
    const float x2 = Q[bq * 3 + 2];
    const float rx = x0 * x0 + x1 * x1 + x2 * x2;

    float s = (__uint_as_float(umin[g]) - BIAS) + rx;

    #pragma unroll
    for (int off = 32; off > 0; off >>= 1)
        s += __shfl_down(s, off, 64);

    __shared__ float red[TPB2 / 64];
    const int lane = threadIdx.x & 63;
    const int wid  = threadIdx.x >> 6;
    if (lane == 0) red[wid] = s;
    __syncthreads();
    if (threadIdx.x == 0) {
        float t = 0.0f;
        #pragma unroll
        for (int w = 0; w < TPB2 / 64; ++w) t += red[w];
        atomicAdd(out, t);
    }
}

extern "C" void kernel_launch(void* const* d_in, const int* in_sizes, int n_in,
                              void* d_out, int out_size, void* d_ws, size_t ws_size,
                              hipStream_t stream) {
    const float* preds = (const float*)d_in[0];
    const float* gts   = (const float*)d_in[1];
    float* out = (float*)d_out;
    unsigned int* umin = (unsigned int*)d_ws;   // 2*8*4096 uints = 256 KiB

    const size_t umin_bytes = (size_t)2 * BATCH * NPTS * sizeof(unsigned int);
    hipMemsetAsync(umin, 0xFF, umin_bytes, stream);   // uint max = +inf sentinel
    hipMemsetAsync(out, 0, sizeof(float), stream);

    chamfer_stage1<<<dim3(2 * BATCH * NSLICE), TPB1, 0, stream>>>(preds, gts, umin);
    chamfer_stage2<<<dim3(2 * BATCH * NPTS / TPB2), TPB2, 0, stream>>>(preds, gts, umin, out);
}